// Round 13
// baseline (245.321 us; speedup 1.0000x reference)
//
#include <hip/hip_runtime.h>

// GAT block, B=8, N=2048, F=64.
// out = softmax(mask_adj(relu(s1_i+s2_j+ab1))) @ h1  +  h2
//   h1 = x@W1^T + b1 ; h2 = x@W2^T + b2 (identity-mask layer is exactly h2)
// p_ij = adj ? max(exp(t_i)*exp(s2_j), 1) : 0
// R13: FUSED single kernel = R10's proven attn body + prep phase + device-wide
// spin barrier. All 512 blocks co-resident (2/CU: LDS 73.7KB, VGPR<=128 via
// launch_bounds) => spin barrier is deadlock-free. Counter zeroed each launch
// via hipMemsetAsync (graph-capturable). adj prefetch issued BEFORE the
// barrier so the HBM stream starts during the prep tail.

#define DEVI __device__ __forceinline__

typedef __attribute__((ext_vector_type(8))) short short8;
typedef __attribute__((ext_vector_type(4))) float floatx4;

DEVI unsigned short f2bf(float x) {
    unsigned u = __builtin_bit_cast(unsigned, x);
    unsigned r = u + 0x7FFFu + ((u >> 16) & 1u);
    return (unsigned short)(r >> 16);
}

DEVI short8 pack8(const float* v) {
    short8 r;
#pragma unroll
    for (int i = 0; i < 8; ++i) r[i] = (short)f2bf(v[i]);
    return r;
}

DEVI unsigned cvt_pk_bf16(float lo, float hi) {
    unsigned r;
    asm("v_cvt_pk_bf16_f32 %0, %1, %2" : "=v"(r) : "v"(lo), "v"(hi));
    return r;
}

// block barrier with LDS-visibility only; does NOT drain vmcnt
DEVI void team_sync() {
    __builtin_amdgcn_sched_barrier(0);
    asm volatile("s_waitcnt lgkmcnt(0)" ::: "memory");
    __builtin_amdgcn_s_barrier();
    __builtin_amdgcn_sched_barrier(0);
}

// grid 512 (bb = blockIdx&7, i-tile = blockIdx>>3, 32 rows), block 512
// = 8 waves = 2 row-groups (wrow) x 4 j-teams (t). Team t: chunks [8t,8t+8).
__global__ __launch_bounds__(512, 4) void k_fused(
    const float* __restrict__ x, const int* __restrict__ adj,
    const float* __restrict__ W1, const float* __restrict__ b1,
    const float* __restrict__ a1, const float* __restrict__ ab1,
    const float* __restrict__ W2, const float* __restrict__ b2,
    unsigned short* __restrict__ hT1,   // ws: [8][64][2048] bf16
    float* __restrict__ expt1,          // ws: [8*2048] exp(s1+ab1)
    float* __restrict__ expv,           // ws: [8*2048] exp(s2)
    int* __restrict__ ctr,              // ws: barrier counter (memset 0 per launch)
    float* __restrict__ out)
{
    __shared__ __align__(16) unsigned short hl[4][2][64][64];  // 65.5 KB, swizzled
    __shared__ __align__(16) float vlds[2048];                 // 8 KB

    const int tid = threadIdx.x;
    const int w = tid >> 6, lane = tid & 63;
    const int g = lane >> 4, r15 = lane & 15;

    // ================= PREP PHASE (blocks 0..255, tid<256) ==================
    // Identical math to the old k_prep (64 rows per prep-block).
    if (blockIdx.x < 256 && tid < 256) {
        const int blockRow = blockIdx.x * 64;
        const int prow = blockRow + w * 16;

        float xa[8], xb[8];
        const float* xrow = x + (long)(prow + r15) * 64;
#pragma unroll
        for (int e = 0; e < 8; ++e) { xa[e] = xrow[g * 8 + e]; xb[e] = xrow[32 + g * 8 + e]; }
        short8 A0 = pack8(xa), A1 = pack8(xb);

        floatx4 pacc[4];
#pragma unroll
        for (int nt = 0; nt < 4; ++nt) {
            float wa[8], wb[8];
            const float* wrow = W1 + (nt * 16 + r15) * 64;
#pragma unroll
            for (int e = 0; e < 8; ++e) { wa[e] = wrow[g * 8 + e]; wb[e] = wrow[32 + g * 8 + e]; }
            short8 B0 = pack8(wa), B1 = pack8(wb);
            floatx4 c = {0.f, 0.f, 0.f, 0.f};
            c = __builtin_amdgcn_mfma_f32_16x16x32_bf16(A0, B0, c, 0, 0, 0);
            c = __builtin_amdgcn_mfma_f32_16x16x32_bf16(A1, B1, c, 0, 0, 0);
            float bias = b1[nt * 16 + r15];
#pragma unroll
            for (int q = 0; q < 4; ++q) c[q] += bias;
            pacc[nt] = c;
        }

        float a1lo[4], a1hi[4];
#pragma unroll
        for (int nt = 0; nt < 4; ++nt) {
            a1lo[nt] = a1[nt * 16 + r15];
            a1hi[nt] = a1[64 + nt * 16 + r15];
        }
#pragma unroll
        for (int q = 0; q < 4; ++q) {
            float s1 = 0.f, s2 = 0.f;
#pragma unroll
            for (int nt = 0; nt < 4; ++nt) { s1 += pacc[nt][q] * a1lo[nt]; s2 += pacc[nt][q] * a1hi[nt]; }
#pragma unroll
            for (int m = 1; m < 16; m <<= 1) { s1 += __shfl_xor(s1, m); s2 += __shfl_xor(s2, m); }
            if (r15 == 0) {
                expt1[prow + 4 * g + q] = __expf(s1 + ab1[0]);
                expv[prow + 4 * g + q]  = __expf(s2);
            }
        }

        unsigned short (*hstage)[72] = (unsigned short (*)[72])&hl[0][0][0][0];  // 9.2 KB alias
#pragma unroll
        for (int nt = 0; nt < 4; ++nt)
#pragma unroll
            for (int q = 0; q < 4; ++q)
                hstage[nt * 16 + r15][w * 16 + 4 * g + q] = f2bf(pacc[nt][q]);
    }
    __syncthreads();
    if (blockIdx.x < 256 && tid < 256) {
        unsigned short (*hstage)[72] = (unsigned short (*)[72])&hl[0][0][0][0];
        const int blockRow = blockIdx.x * 64;
        const int o = tid >> 2, seg = (tid & 3) * 16;
        const int pb = blockRow >> 11;
        const int ib = blockRow & 2047;
        unsigned short* dst = hT1 + ((long)(pb * 64 + o) * 2048) + ib + seg;
        uint4 v0 = *(const uint4*)&hstage[o][seg];
        uint4 v1 = *(const uint4*)&hstage[o][seg + 8];
        *(uint4*)dst = v0;
        *(uint4*)(dst + 8) = v1;
    }

    // ================= ATTN SETUP + adj prefetch (pre-barrier) ==============
    const int t = w >> 1, wrow = w & 1;
    const int bb = blockIdx.x & 7;
    const int it = blockIdx.x >> 3;
    const int rowbase = it * 32 + wrow * 16;
    const int jt0 = t * 8;

    const int4* adjq = (const int4*)(adj + (long)(bb * 2048 + rowbase + r15) * 2048);
    int4 adjR[2][4];

#define ADJ(c) do {                                                            \
        const int base_ = (jt0 + (c)) * 16 + g * 2;                            \
        adjR[(c) & 1][0] = adjq[base_];                                        \
        adjR[(c) & 1][1] = adjq[base_ + 1];                                    \
        adjR[(c) & 1][2] = adjq[base_ + 8];                                    \
        adjR[(c) & 1][3] = adjq[base_ + 9];                                    \
    } while (0)

    ADJ(0); ADJ(1);   // in flight across the barrier wait

    // ================= DEVICE-WIDE BARRIER ==================================
    // All 512 blocks co-resident (2/CU guaranteed by LDS 73.7KB + lb(512,4))
    // => spin is deadlock-free. Release/acquire at agent scope for cross-XCD
    // visibility of hT1/expt1/expv (G16).
    __threadfence();
    if (tid == 0) {
        __hip_atomic_fetch_add(ctr, 1, __ATOMIC_ACQ_REL, __HIP_MEMORY_SCOPE_AGENT);
        while (__hip_atomic_load(ctr, __ATOMIC_ACQUIRE, __HIP_MEMORY_SCOPE_AGENT) < 512)
            __builtin_amdgcn_s_sleep(8);
    }
    __syncthreads();
    __threadfence();

    // ================= ATTN PHASE (R10 body, unchanged math) ================
    *(float4*)&vlds[tid * 4] = *(const float4*)&expv[bb * 2048 + tid * 4];

    const float u = expt1[bb * 2048 + rowbase + r15];

    floatx4 acc[4];
#pragma unroll
    for (int nt = 0; nt < 4; ++nt) acc[nt] = (floatx4){0.f, 0.f, 0.f, 0.f};
    floatx4 acc5 = {0.f, 0.f, 0.f, 0.f};

    short8 ones;
#pragma unroll
    for (int i = 0; i < 8; ++i) ones[i] = (short)0x3F80;   // bf16 1.0

    // hT staging: team-local 128 threads; each stages 64 B of one row-half.
    const int ttid = tid & 127;
    const int so = ttid >> 1, ch = ttid & 1;
    const unsigned short* hTsrc = hT1 + (long)(bb * 64 + so) * 2048 + ch * 32;
    unsigned short* hlw = &hl[t][0][0][0];

    uint4 hrg[4];

#define HTLOAD(c) do {                                                         \
        const unsigned short* s_ = hTsrc + (jt0 + (c)) * 64;                   \
        hrg[0] = *(const uint4*)s_;                                            \
        hrg[1] = *(const uint4*)(s_ + 8);                                      \
        hrg[2] = *(const uint4*)(s_ + 16);                                     \
        hrg[3] = *(const uint4*)(s_ + 24);                                     \
    } while (0)

#define HTSTORE(c) do {                                                        \
        const int bo_ = ((c) & 1) * 4096 + so * 64;                            \
        _Pragma("unroll")                                                      \
        for (int k_ = 0; k_ < 4; ++k_)                                         \
            *(uint4*)&hlw[bo_ + (((ch * 4 + k_) ^ (so & 7)) * 8)] = hrg[k_];   \
    } while (0)

#define COMPUTE(C) do {                                                        \
        const int vb_ = (jt0 + (C)) * 64 + g * 8;                              \
        float4 v0_ = *(const float4*)&vlds[vb_];                               \
        float4 v1_ = *(const float4*)&vlds[vb_ + 4];                           \
        float4 v2_ = *(const float4*)&vlds[vb_ + 32];                          \
        float4 v3_ = *(const float4*)&vlds[vb_ + 36];                          \
        int4 j0_ = adjR[(C) & 1][0], j1_ = adjR[(C) & 1][1];                   \
        int4 j2_ = adjR[(C) & 1][2], j3_ = adjR[(C) & 1][3];                   \
        uint4 au_, bu_;                                                        \
        au_.x = cvt_pk_bf16(j0_.x > 0 ? fmaxf(u * v0_.x, 1.f) : 0.f,           \
                            j0_.y > 0 ? fmaxf(u * v0_.y, 1.f) : 0.f);          \
        au_.y = cvt_pk_bf16(j0_.z > 0 ? fmaxf(u * v0_.z, 1.f) : 0.f,           \
                            j0_.w > 0 ? fmaxf(u * v0_.w, 1.f) : 0.f);          \
        au_.z = cvt_pk_bf16(j1_.x > 0 ? fmaxf(u * v1_.x, 1.f) : 0.f,           \
                            j1_.y > 0 ? fmaxf(u * v1_.y, 1.f) : 0.f);          \
        au_.w = cvt_pk_bf16(j1_.z > 0 ? fmaxf(u * v1_.z, 1.f) : 0.f,           \
                            j1_.w > 0 ? fmaxf(u * v1_.w, 1.f) : 0.f);          \
        bu_.x = cvt_pk_bf16(j2_.x > 0 ? fmaxf(u * v2_.x, 1.f) : 0.f,           \
                            j2_.y > 0 ? fmaxf(u * v2_.y, 1.f) : 0.f);          \
        bu_.y = cvt_pk_bf16(j2_.z > 0 ? fmaxf(u * v2_.z, 1.f) : 0.f,           \
                            j2_.w > 0 ? fmaxf(u * v2_.w, 1.f) : 0.f);          \
        bu_.z = cvt_pk_bf16(j3_.x > 0 ? fmaxf(u * v3_.x, 1.f) : 0.f,           \
                            j3_.y > 0 ? fmaxf(u * v3_.y, 1.f) : 0.f);          \
        bu_.w = cvt_pk_bf16(j3_.z > 0 ? fmaxf(u * v3_.z, 1.f) : 0.f,           \
                            j3_.w > 0 ? fmaxf(u * v3_.w, 1.f) : 0.f);          \
        short8 a0 = __builtin_bit_cast(short8, au_);                           \
        short8 a1f = __builtin_bit_cast(short8, bu_);                          \
        const int bufo_ = ((C) & 1) * 4096;                                    \
        const int sw_ = r15 & 7;                                               \
        _Pragma("unroll")                                                      \
        for (int nt_ = 0; nt_ < 4; ++nt_) {                                    \
            const int ro_ = bufo_ + (nt_ * 16 + r15) * 64;                     \
            short8 b0 = *(const short8*)&hlw[ro_ + ((g ^ sw_) * 8)];           \
            short8 b1 = *(const short8*)&hlw[ro_ + (((4 + g) ^ sw_) * 8)];     \
            acc[nt_] = __builtin_amdgcn_mfma_f32_16x16x32_bf16(a0, b0, acc[nt_], 0, 0, 0); \
            acc[nt_] = __builtin_amdgcn_mfma_f32_16x16x32_bf16(a1f, b1, acc[nt_], 0, 0, 0); \
        }                                                                      \
        acc5 = __builtin_amdgcn_mfma_f32_16x16x32_bf16(a0, ones, acc5, 0, 0, 0); \
        acc5 = __builtin_amdgcn_mfma_f32_16x16x32_bf16(a1f, ones, acc5, 0, 0, 0); \
    } while (0)

    // prologue (ADJ(0)/ADJ(1) already in flight from before the barrier)
    HTLOAD(0);
    HTSTORE(0);
    team_sync();

#pragma unroll
    for (int C = 0; C < 8; ++C) {
        if (C < 7) HTLOAD(C + 1);
        COMPUTE(C);
        if (C < 7) HTSTORE(C + 1);
        if (C < 6) ADJ(C + 2);       // WAR ring: after COMPUTE(C)
        team_sync();
    }

#undef COMPUTE
#undef HTSTORE
#undef HTLOAD
#undef ADJ

    // ---- combine 4 teams' partials (reuse hl as scratch) ----
    float* csh = (float*)&hl[0][0][0][0];
    if (t > 0) {
        const int wb = ((t - 1) * 2 + wrow) * 20;
#pragma unroll
        for (int nt = 0; nt < 4; ++nt)
#pragma unroll
            for (int q = 0; q < 4; ++q)
                csh[(wb + nt * 4 + q) * 64 + lane] = acc[nt][q];
#pragma unroll
        for (int q = 0; q < 4; ++q)
            csh[(wb + 16 + q) * 64 + lane] = acc5[q];
    }
    __syncthreads();

    if (t == 0) {
#pragma unroll
        for (int ti = 0; ti < 3; ++ti) {
            const int wb = (ti * 2 + wrow) * 20;
#pragma unroll
            for (int nt = 0; nt < 4; ++nt)
#pragma unroll
                for (int q = 0; q < 4; ++q)
                    acc[nt][q] += csh[(wb + nt * 4 + q) * 64 + lane];
#pragma unroll
            for (int q = 0; q < 4; ++q)
                acc5[q] += csh[(wb + 16 + q) * 64 + lane];
        }
        float linv[4];
#pragma unroll
        for (int q = 0; q < 4; ++q) linv[q] = 1.0f / acc5[q];

        // h2 = x@W2^T + b2 (identity-mask layer) + store
        float xa[8], xb[8];
        const float* xrow = x + ((long)(bb * 2048 + rowbase + r15)) * 64;
#pragma unroll
        for (int e = 0; e < 8; ++e) { xa[e] = xrow[g * 8 + e]; xb[e] = xrow[32 + g * 8 + e]; }
        short8 A0 = pack8(xa), A1 = pack8(xb);
#pragma unroll
        for (int nt = 0; nt < 4; ++nt) {
            float wa[8], wb[8];
            const float* wrow2 = W2 + (nt * 16 + r15) * 64;
#pragma unroll
            for (int e = 0; e < 8; ++e) { wa[e] = wrow2[g * 8 + e]; wb[e] = wrow2[32 + g * 8 + e]; }
            short8 B0 = pack8(wa), B1 = pack8(wb);
            floatx4 c = {0.f, 0.f, 0.f, 0.f};
            c = __builtin_amdgcn_mfma_f32_16x16x32_bf16(A0, B0, c, 0, 0, 0);
            c = __builtin_amdgcn_mfma_f32_16x16x32_bf16(A1, B1, c, 0, 0, 0);
            float bias = b2[nt * 16 + r15];
#pragma unroll
            for (int q = 0; q < 4; ++q) {
                float val = acc[nt][q] * linv[q] + c[q] + bias;
                out[((long)(bb * 2048 + rowbase + 4 * g + q)) * 64 + nt * 16 + r15] = val;
            }
        }
    }
}

extern "C" void kernel_launch(void* const* d_in, const int* in_sizes, int n_in,
                              void* d_out, int out_size, void* d_ws, size_t ws_size,
                              hipStream_t stream) {
    const float* x   = (const float*)d_in[0];
    const int*   adj = (const int*)d_in[1];
    // d_in[2] identity: unused (mask == I exactly -> layer2 == h2)
    const float* W1  = (const float*)d_in[3];
    const float* b1  = (const float*)d_in[4];
    const float* a1  = (const float*)d_in[5];
    const float* ab1 = (const float*)d_in[6];
    const float* W2  = (const float*)d_in[7];
    const float* b2  = (const float*)d_in[8];
    // d_in[9] a2, d_in[10] ab2: unused

    unsigned short* hT1 = (unsigned short*)d_ws;                       // 2 MB
    float* expt1 = (float*)((char*)d_ws + (size_t)8 * 64 * 2048 * 2);  // 64 KB
    float* expv  = expt1 + 8 * 2048;                                   // 64 KB
    int*   ctr   = (int*)(expv + 8 * 2048);                            // 4 B

    hipMemsetAsync(ctr, 0, sizeof(int), stream);   // deterministic barrier reset
    k_fused<<<512, 512, 0, stream>>>(x, adj, W1, b1, a1, ab1, W2, b2,
                                     hT1, expt1, expv, ctr, (float*)d_out);
}

// Round 14
// 39.662 us; speedup vs baseline: 6.1853x; 6.1853x over previous
//
#include <hip/hip_runtime.h>

// GAT block, B=8, N=2048, F=64.
// out = softmax(mask_adj(relu(s1_i+s2_j+ab1))) @ h1  +  h2
//   h1 = x@W1^T + b1 ; h2 = x@W2^T + b2 (identity-mask layer is exactly h2)
// p_ij = adj ? exp(relu(t_i+s2_j)) : 0 = adj ? max(exp(t_i)*exp(s2_j), 1) : 0
// R14 = exact revert to R8 (verified best: 39.568 us, absmax 0.015625).
// R11-R13 post-mortem: phase-split and manual spin-barrier fusion both
// regressed badly (scratch spill of hot-loop state + fence/poll storm).
// R8 keeps adj loads pipelined inside the compute loop, which is the
// empirically fastest structure across all 13 variants tested.

#define DEVI __device__ __forceinline__

typedef __attribute__((ext_vector_type(8))) short short8;
typedef __attribute__((ext_vector_type(4))) float floatx4;

DEVI unsigned short f2bf(float x) {
    unsigned u = __builtin_bit_cast(unsigned, x);
    unsigned r = u + 0x7FFFu + ((u >> 16) & 1u);
    return (unsigned short)(r >> 16);
}

DEVI short8 pack8(const float* v) {
    short8 r;
#pragma unroll
    for (int i = 0; i < 8; ++i) r[i] = (short)f2bf(v[i]);
    return r;
}

DEVI unsigned cvt_pk_bf16(float lo, float hi) {
    unsigned r;
    asm("v_cvt_pk_bf16_f32 %0, %1, %2" : "=v"(r) : "v"(lo), "v"(hi));
    return r;
}

// block barrier with LDS-visibility only; does NOT drain vmcnt (prefetch lives)
DEVI void team_sync() {
    __builtin_amdgcn_sched_barrier(0);
    asm volatile("s_waitcnt lgkmcnt(0)" ::: "memory");
    __builtin_amdgcn_s_barrier();
    __builtin_amdgcn_sched_barrier(0);
}

// ---------------- Kernel 1: h1^T (bf16), u = exp(s1+ab1), v = exp(s2) -------
__global__ __launch_bounds__(256) void k_prep(
    const float* __restrict__ x, const float* __restrict__ W1,
    const float* __restrict__ b1, const float* __restrict__ a1,
    const float* __restrict__ ab1,
    unsigned short* __restrict__ hT1,   // [8][64][2048] bf16
    float* __restrict__ expt1,          // [8*2048]  exp(s1+ab1)
    float* __restrict__ expv)           // [8*2048]  exp(s2)
{
    __shared__ __align__(16) unsigned short hstage[64][72];
    const int tid = threadIdx.x;
    const int w = tid >> 6, lane = tid & 63;
    const int g = lane >> 4, r15 = lane & 15;
    const int blockRow = blockIdx.x * 64;
    const int rowbase = blockRow + w * 16;

    float xa[8], xb[8];
    const float* xrow = x + (long)(rowbase + r15) * 64;
#pragma unroll
    for (int e = 0; e < 8; ++e) { xa[e] = xrow[g * 8 + e]; xb[e] = xrow[32 + g * 8 + e]; }
    short8 A0 = pack8(xa), A1 = pack8(xb);

    floatx4 acc[4];
#pragma unroll
    for (int nt = 0; nt < 4; ++nt) {
        float wa[8], wb[8];
        const float* wrow = W1 + (nt * 16 + r15) * 64;
#pragma unroll
        for (int e = 0; e < 8; ++e) { wa[e] = wrow[g * 8 + e]; wb[e] = wrow[32 + g * 8 + e]; }
        short8 B0 = pack8(wa), B1 = pack8(wb);
        floatx4 c = {0.f, 0.f, 0.f, 0.f};
        c = __builtin_amdgcn_mfma_f32_16x16x32_bf16(A0, B0, c, 0, 0, 0);
        c = __builtin_amdgcn_mfma_f32_16x16x32_bf16(A1, B1, c, 0, 0, 0);
        float bias = b1[nt * 16 + r15];
#pragma unroll
        for (int q = 0; q < 4; ++q) c[q] += bias;
        acc[nt] = c;
    }

    float a1lo[4], a1hi[4];
#pragma unroll
    for (int nt = 0; nt < 4; ++nt) {
        a1lo[nt] = a1[nt * 16 + r15];
        a1hi[nt] = a1[64 + nt * 16 + r15];
    }
    float s1q[4], s2q[4];
#pragma unroll
    for (int q = 0; q < 4; ++q) {
        float s1 = 0.f, s2 = 0.f;
#pragma unroll
        for (int nt = 0; nt < 4; ++nt) { s1 += acc[nt][q] * a1lo[nt]; s2 += acc[nt][q] * a1hi[nt]; }
#pragma unroll
        for (int m = 1; m < 16; m <<= 1) { s1 += __shfl_xor(s1, m); s2 += __shfl_xor(s2, m); }
        s1q[q] = s1; s2q[q] = s2;
    }
    if (r15 == 0) {
        float abv = ab1[0];
#pragma unroll
        for (int q = 0; q < 4; ++q) {
            expt1[rowbase + 4 * g + q] = __expf(s1q[q] + abv);
            expv[rowbase + 4 * g + q]  = __expf(s2q[q]);
        }
    }

#pragma unroll
    for (int nt = 0; nt < 4; ++nt)
#pragma unroll
        for (int q = 0; q < 4; ++q)
            hstage[nt * 16 + r15][w * 16 + 4 * g + q] = f2bf(acc[nt][q]);
    __syncthreads();
    {
        const int o = tid >> 2, seg = (tid & 3) * 16;
        const int bb = blockRow >> 11;
        const int ib = blockRow & 2047;
        unsigned short* dst = hT1 + ((long)(bb * 64 + o) * 2048) + ib + seg;
        uint4 v0 = *(const uint4*)&hstage[o][seg];
        uint4 v1 = *(const uint4*)&hstage[o][seg + 8];
        *(uint4*)dst = v0;
        *(uint4*)(dst + 8) = v1;
    }
}

// ---------------- Kernel 2: masked softmax @ h1 + h2 ------------------------
// grid 256 (bb = blockIdx&7, i-tile = blockIdx>>3), block 1024 = 16 waves
// = 4 row-groups (wrow) x 4 j-teams (t). Team t owns chunks [8t, 8t+8).
__global__ __launch_bounds__(1024, 4) void k_attn(
    const float* __restrict__ x, const int* __restrict__ adj,
    const float* __restrict__ W2, const float* __restrict__ b2,
    const unsigned short* __restrict__ hT1,
    const float* __restrict__ expt1, const float* __restrict__ expv,
    float* __restrict__ out)
{
    __shared__ __align__(16) unsigned short hl[4][2][64][72];  // 73.7 KB
    __shared__ __align__(16) float vlds[2048];                 // 8 KB

    const int tid = threadIdx.x;
    const int w = tid >> 6, lane = tid & 63;
    const int t = w >> 2, wrow = w & 3;
    const int g = lane >> 4, r15 = lane & 15;
    const int bb = blockIdx.x & 7;
    const int it = blockIdx.x >> 3;
    const int rowbase = it * 64 + wrow * 16;
    const int jt0 = t * 8;

    // stage exp(s2) for the whole batch row-block once
    *(float2*)&vlds[tid * 2] = *(const float2*)&expv[bb * 2048 + tid * 2];

    const float u = expt1[bb * 2048 + rowbase + r15];   // this lane's row factor

    floatx4 acc[4];
#pragma unroll
    for (int nt = 0; nt < 4; ++nt) acc[nt] = (floatx4){0.f, 0.f, 0.f, 0.f};
    floatx4 acc5 = {0.f, 0.f, 0.f, 0.f};

    short8 ones;
#pragma unroll
    for (int i = 0; i < 8; ++i) ones[i] = (short)0x3F80;   // bf16 1.0

    const int4* adjq = (const int4*)(adj + (long)(bb * 2048 + rowbase + r15) * 2048);

    // hl staging: team-local 256 threads cover 64 f-rows x 64 j
    const int ttid = tid & 255;
    const int so = ttid >> 2, sseg = (ttid & 3) * 16;
    const unsigned short* hTsrc = hT1 + (long)(bb * 64 + so) * 2048 + sseg;
    unsigned short* hldst0 = &hl[t][0][so][sseg];
    unsigned short* hldst1 = &hl[t][1][so][sseg];

    int4 adjR[2][4];
    uint4 hrg[2][2];

#define ADJ(c) do {                                                            \
        const int base_ = (jt0 + (c)) * 16 + g * 2;                            \
        adjR[(c) & 1][0] = adjq[base_];                                        \
        adjR[(c) & 1][1] = adjq[base_ + 1];                                    \
        adjR[(c) & 1][2] = adjq[base_ + 8];                                    \
        adjR[(c) & 1][3] = adjq[base_ + 9];                                    \
    } while (0)

#define HTLOAD(c) do {                                                         \
        const unsigned short* s_ = hTsrc + (jt0 + (c)) * 64;                   \
        hrg[(c) & 1][0] = *(const uint4*)s_;                                   \
        hrg[(c) & 1][1] = *(const uint4*)(s_ + 8);                             \
    } while (0)

#define HTSTORE(c) do {                                                        \
        unsigned short* d_ = ((c) & 1) ? hldst1 : hldst0;                      \
        *(uint4*)d_ = hrg[(c) & 1][0];                                         \
        *(uint4*)(d_ + 8) = hrg[(c) & 1][1];                                   \
    } while (0)

#define COMPUTE(C) do {                                                        \
        const int vb_ = (jt0 + (C)) * 64 + g * 8;                              \
        float4 v0_ = *(const float4*)&vlds[vb_];                               \
        float4 v1_ = *(const float4*)&vlds[vb_ + 4];                           \
        float4 v2_ = *(const float4*)&vlds[vb_ + 32];                          \
        float4 v3_ = *(const float4*)&vlds[vb_ + 36];                          \
        int4 j0_ = adjR[(C) & 1][0], j1_ = adjR[(C) & 1][1];                   \
        int4 j2_ = adjR[(C) & 1][2], j3_ = adjR[(C) & 1][3];                   \
        uint4 au_, bu_;                                                        \
        au_.x = cvt_pk_bf16(j0_.x > 0 ? fmaxf(u * v0_.x, 1.f) : 0.f,           \
                            j0_.y > 0 ? fmaxf(u * v0_.y, 1.f) : 0.f);          \
        au_.y = cvt_pk_bf16(j0_.z > 0 ? fmaxf(u * v0_.z, 1.f) : 0.f,           \
                            j0_.w > 0 ? fmaxf(u * v0_.w, 1.f) : 0.f);          \
        au_.z = cvt_pk_bf16(j1_.x > 0 ? fmaxf(u * v1_.x, 1.f) : 0.f,           \
                            j1_.y > 0 ? fmaxf(u * v1_.y, 1.f) : 0.f);          \
        au_.w = cvt_pk_bf16(j1_.z > 0 ? fmaxf(u * v1_.z, 1.f) : 0.f,           \
                            j1_.w > 0 ? fmaxf(u * v1_.w, 1.f) : 0.f);          \
        bu_.x = cvt_pk_bf16(j2_.x > 0 ? fmaxf(u * v2_.x, 1.f) : 0.f,           \
                            j2_.y > 0 ? fmaxf(u * v2_.y, 1.f) : 0.f);          \
        bu_.y = cvt_pk_bf16(j2_.z > 0 ? fmaxf(u * v2_.z, 1.f) : 0.f,           \
                            j2_.w > 0 ? fmaxf(u * v2_.w, 1.f) : 0.f);          \
        bu_.z = cvt_pk_bf16(j3_.x > 0 ? fmaxf(u * v3_.x, 1.f) : 0.f,           \
                            j3_.y > 0 ? fmaxf(u * v3_.y, 1.f) : 0.f);          \
        bu_.w = cvt_pk_bf16(j3_.z > 0 ? fmaxf(u * v3_.z, 1.f) : 0.f,           \
                            j3_.w > 0 ? fmaxf(u * v3_.w, 1.f) : 0.f);          \
        short8 a0 = __builtin_bit_cast(short8, au_);                           \
        short8 a1 = __builtin_bit_cast(short8, bu_);                           \
        _Pragma("unroll")                                                      \
        for (int nt_ = 0; nt_ < 4; ++nt_) {                                    \
            short8 b0 = *(const short8*)&hl[t][(C) & 1][nt_ * 16 + r15][g * 8];      \
            short8 b1 = *(const short8*)&hl[t][(C) & 1][nt_ * 16 + r15][32 + g * 8]; \
            acc[nt_] = __builtin_amdgcn_mfma_f32_16x16x32_bf16(a0, b0, acc[nt_], 0, 0, 0); \
            acc[nt_] = __builtin_amdgcn_mfma_f32_16x16x32_bf16(a1, b1, acc[nt_], 0, 0, 0); \
        }                                                                      \
        acc5 = __builtin_amdgcn_mfma_f32_16x16x32_bf16(a0, ones, acc5, 0, 0, 0); \
        acc5 = __builtin_amdgcn_mfma_f32_16x16x32_bf16(a1, ones, acc5, 0, 0, 0); \
    } while (0)

    // prologue: adj chunks 0,1 in flight; hl[0] staged; hT chunk 1 in regs
    ADJ(0); ADJ(1);
    HTLOAD(0);
    HTSTORE(0);
    HTLOAD(1);
    team_sync();

    // NOTE: ADJ(C+2) must come AFTER COMPUTE(C) — it reuses slot adjR[C&1]
    // (WAR on the ring).
#pragma unroll
    for (int C = 0; C < 8; ++C) {
        if (C < 6) HTLOAD(C + 2);       // -> hrg[C&1] (chunk C already stored)
        if (C < 7) HTSTORE(C + 1);      // hl[(C+1)&1] <- hrg[(C+1)&1]
        COMPUTE(C);                     // reads adjR[C&1], hl[C&1]
        if (C < 6) ADJ(C + 2);          // -> adjR[C&1], after its last read
        team_sync();
    }

#undef COMPUTE
#undef HTSTORE
#undef HTLOAD
#undef ADJ

    // ---- combine 4 teams' partials (reuse hl as scratch; all computes done) ----
    float* csh = (float*)&hl[0][0][0][0];   // 12 waves x 20 x 64 f32 = 60 KB
    if (t > 0) {
        const int wb = ((t - 1) * 4 + wrow) * 20;
#pragma unroll
        for (int nt = 0; nt < 4; ++nt)
#pragma unroll
            for (int q = 0; q < 4; ++q)
                csh[(wb + nt * 4 + q) * 64 + lane] = acc[nt][q];
#pragma unroll
        for (int q = 0; q < 4; ++q)
            csh[(wb + 16 + q) * 64 + lane] = acc5[q];
    }
    __syncthreads();

    if (t == 0) {
#pragma unroll
        for (int ti = 0; ti < 3; ++ti) {
            const int wb = (ti * 4 + wrow) * 20;
#pragma unroll
            for (int nt = 0; nt < 4; ++nt)
#pragma unroll
                for (int q = 0; q < 4; ++q)
                    acc[nt][q] += csh[(wb + nt * 4 + q) * 64 + lane];
#pragma unroll
            for (int q = 0; q < 4; ++q)
                acc5[q] += csh[(wb + 16 + q) * 64 + lane];
        }
        float linv[4];
#pragma unroll
        for (int q = 0; q < 4; ++q) linv[q] = 1.0f / acc5[q];

        // h2 = x@W2^T + b2 (identity-mask layer) + store
        float xa[8], xb[8];
        const float* xrow = x + ((long)(bb * 2048 + rowbase + r15)) * 64;
#pragma unroll
        for (int e = 0; e < 8; ++e) { xa[e] = xrow[g * 8 + e]; xb[e] = xrow[32 + g * 8 + e]; }
        short8 A0 = pack8(xa), A1 = pack8(xb);
#pragma unroll
        for (int nt = 0; nt < 4; ++nt) {
            float wa[8], wb[8];
            const float* wrow2 = W2 + (nt * 16 + r15) * 64;
#pragma unroll
            for (int e = 0; e < 8; ++e) { wa[e] = wrow2[g * 8 + e]; wb[e] = wrow2[32 + g * 8 + e]; }
            short8 B0 = pack8(wa), B1 = pack8(wb);
            floatx4 c = {0.f, 0.f, 0.f, 0.f};
            c = __builtin_amdgcn_mfma_f32_16x16x32_bf16(A0, B0, c, 0, 0, 0);
            c = __builtin_amdgcn_mfma_f32_16x16x32_bf16(A1, B1, c, 0, 0, 0);
            float bias = b2[nt * 16 + r15];
#pragma unroll
            for (int q = 0; q < 4; ++q) {
                float val = acc[nt][q] * linv[q] + c[q] + bias;
                out[((long)(bb * 2048 + rowbase + 4 * g + q)) * 64 + nt * 16 + r15] = val;
            }
        }
    }
}

extern "C" void kernel_launch(void* const* d_in, const int* in_sizes, int n_in,
                              void* d_out, int out_size, void* d_ws, size_t ws_size,
                              hipStream_t stream) {
    const float* x   = (const float*)d_in[0];
    const int*   adj = (const int*)d_in[1];
    // d_in[2] identity: unused (mask == I exactly -> layer2 == h2)
    const float* W1  = (const float*)d_in[3];
    const float* b1  = (const float*)d_in[4];
    const float* a1  = (const float*)d_in[5];
    const float* ab1 = (const float*)d_in[6];
    const float* W2  = (const float*)d_in[7];
    const float* b2  = (const float*)d_in[8];
    // d_in[9] a2, d_in[10] ab2: unused

    unsigned short* hT1 = (unsigned short*)d_ws;                 // 2 MB
    float* expt1 = (float*)((char*)d_ws + (size_t)8 * 64 * 2048 * 2);
    float* expv  = expt1 + 8 * 2048;

    k_prep<<<256, 256, 0, stream>>>(x, W1, b1, a1, ab1, hT1, expt1, expv);
    k_attn<<<256, 1024, 0, stream>>>(x, adj, W2, b2, hT1, expt1, expv, (float*)d_out);
}

// Round 15
// 39.485 us; speedup vs baseline: 6.2131x; 1.0045x over previous
//
#include <hip/hip_runtime.h>

// GAT block, B=8, N=2048, F=64.
// out = softmax(mask_adj(relu(s1_i+s2_j+ab1))) @ h1  +  h2
//   h1 = x@W1^T + b1 ; h2 = x@W2^T + b2 (identity-mask layer is exactly h2)
// p_ij = adj ? exp(relu(t_i+s2_j)) : 0 = adj ? max(exp(t_i)*exp(s2_j), 1) : 0
// R15 = R8/R14's k_attn (banked optimum, untouched) + k_prep split to
// 512 blocks x 128 thr (32 rows/block, 2 blocks/CU) to cut prep wall time.

#define DEVI __device__ __forceinline__

typedef __attribute__((ext_vector_type(8))) short short8;
typedef __attribute__((ext_vector_type(4))) float floatx4;

DEVI unsigned short f2bf(float x) {
    unsigned u = __builtin_bit_cast(unsigned, x);
    unsigned r = u + 0x7FFFu + ((u >> 16) & 1u);
    return (unsigned short)(r >> 16);
}

DEVI short8 pack8(const float* v) {
    short8 r;
#pragma unroll
    for (int i = 0; i < 8; ++i) r[i] = (short)f2bf(v[i]);
    return r;
}

DEVI unsigned cvt_pk_bf16(float lo, float hi) {
    unsigned r;
    asm("v_cvt_pk_bf16_f32 %0, %1, %2" : "=v"(r) : "v"(lo), "v"(hi));
    return r;
}

// block barrier with LDS-visibility only; does NOT drain vmcnt (prefetch lives)
DEVI void team_sync() {
    __builtin_amdgcn_sched_barrier(0);
    asm volatile("s_waitcnt lgkmcnt(0)" ::: "memory");
    __builtin_amdgcn_s_barrier();
    __builtin_amdgcn_sched_barrier(0);
}

// ---------------- Kernel 1: h1^T (bf16), u = exp(s1+ab1), v = exp(s2) -------
// 512 blocks x 128 thr: 32 rows/block (2 waves x 16 rows), 2 blocks/CU so the
// serial MFMA->shuffle->exp chains of independent blocks overlap.
__global__ __launch_bounds__(128) void k_prep(
    const float* __restrict__ x, const float* __restrict__ W1,
    const float* __restrict__ b1, const float* __restrict__ a1,
    const float* __restrict__ ab1,
    unsigned short* __restrict__ hT1,   // [8][64][2048] bf16
    float* __restrict__ expt1,          // [8*2048]  exp(s1+ab1)
    float* __restrict__ expv)           // [8*2048]  exp(s2)
{
    __shared__ __align__(16) unsigned short hstage[64][40];   // [f][row-in-tile]
    const int tid = threadIdx.x;
    const int w = tid >> 6, lane = tid & 63;
    const int g = lane >> 4, r15 = lane & 15;
    const int blockRow = blockIdx.x * 32;
    const int rowbase = blockRow + w * 16;

    float xa[8], xb[8];
    const float* xrow = x + (long)(rowbase + r15) * 64;
#pragma unroll
    for (int e = 0; e < 8; ++e) { xa[e] = xrow[g * 8 + e]; xb[e] = xrow[32 + g * 8 + e]; }
    short8 A0 = pack8(xa), A1 = pack8(xb);

    floatx4 acc[4];
#pragma unroll
    for (int nt = 0; nt < 4; ++nt) {
        float wa[8], wb[8];
        const float* wrow = W1 + (nt * 16 + r15) * 64;
#pragma unroll
        for (int e = 0; e < 8; ++e) { wa[e] = wrow[g * 8 + e]; wb[e] = wrow[32 + g * 8 + e]; }
        short8 B0 = pack8(wa), B1 = pack8(wb);
        floatx4 c = {0.f, 0.f, 0.f, 0.f};
        c = __builtin_amdgcn_mfma_f32_16x16x32_bf16(A0, B0, c, 0, 0, 0);
        c = __builtin_amdgcn_mfma_f32_16x16x32_bf16(A1, B1, c, 0, 0, 0);
        float bias = b1[nt * 16 + r15];
#pragma unroll
        for (int q = 0; q < 4; ++q) c[q] += bias;
        acc[nt] = c;
    }

    float a1lo[4], a1hi[4];
#pragma unroll
    for (int nt = 0; nt < 4; ++nt) {
        a1lo[nt] = a1[nt * 16 + r15];
        a1hi[nt] = a1[64 + nt * 16 + r15];
    }
    float s1q[4], s2q[4];
#pragma unroll
    for (int q = 0; q < 4; ++q) {
        float s1 = 0.f, s2 = 0.f;
#pragma unroll
        for (int nt = 0; nt < 4; ++nt) { s1 += acc[nt][q] * a1lo[nt]; s2 += acc[nt][q] * a1hi[nt]; }
#pragma unroll
        for (int m = 1; m < 16; m <<= 1) { s1 += __shfl_xor(s1, m); s2 += __shfl_xor(s2, m); }
        s1q[q] = s1; s2q[q] = s2;
    }
    if (r15 == 0) {
        float abv = ab1[0];
#pragma unroll
        for (int q = 0; q < 4; ++q) {
            expt1[rowbase + 4 * g + q] = __expf(s1q[q] + abv);
            expv[rowbase + 4 * g + q]  = __expf(s2q[q]);
        }
    }

#pragma unroll
    for (int nt = 0; nt < 4; ++nt)
#pragma unroll
        for (int q = 0; q < 4; ++q)
            hstage[nt * 16 + r15][w * 16 + 4 * g + q] = f2bf(acc[nt][q]);
    __syncthreads();
    {
        // 128 threads write 64 f-rows x 32 node-rows: 2 threads/f-row, 32 B each
        const int o = tid >> 1, half = tid & 1;
        const int bb = blockRow >> 11;
        const int ib = blockRow & 2047;
        unsigned short* dst = hT1 + ((long)(bb * 64 + o) * 2048) + ib + half * 16;
        uint4 v0 = *(const uint4*)&hstage[o][half * 16];
        uint4 v1 = *(const uint4*)&hstage[o][half * 16 + 8];
        *(uint4*)dst = v0;
        *(uint4*)(dst + 8) = v1;
    }
}

// ---------------- Kernel 2: masked softmax @ h1 + h2 ------------------------
// UNCHANGED from R8/R14 (banked optimum: 39.6 us total, absmax 0.015625).
// grid 256 (bb = blockIdx&7, i-tile = blockIdx>>3), block 1024 = 16 waves
// = 4 row-groups (wrow) x 4 j-teams (t). Team t owns chunks [8t, 8t+8).
__global__ __launch_bounds__(1024, 4) void k_attn(
    const float* __restrict__ x, const int* __restrict__ adj,
    const float* __restrict__ W2, const float* __restrict__ b2,
    const unsigned short* __restrict__ hT1,
    const float* __restrict__ expt1, const float* __restrict__ expv,
    float* __restrict__ out)
{
    __shared__ __align__(16) unsigned short hl[4][2][64][72];  // 73.7 KB
    __shared__ __align__(16) float vlds[2048];                 // 8 KB

    const int tid = threadIdx.x;
    const int w = tid >> 6, lane = tid & 63;
    const int t = w >> 2, wrow = w & 3;
    const int g = lane >> 4, r15 = lane & 15;
    const int bb = blockIdx.x & 7;
    const int it = blockIdx.x >> 3;
    const int rowbase = it * 64 + wrow * 16;
    const int jt0 = t * 8;

    // stage exp(s2) for the whole batch row-block once
    *(float2*)&vlds[tid * 2] = *(const float2*)&expv[bb * 2048 + tid * 2];

    const float u = expt1[bb * 2048 + rowbase + r15];   // this lane's row factor

    floatx4 acc[4];
#pragma unroll
    for (int nt = 0; nt < 4; ++nt) acc[nt] = (floatx4){0.f, 0.f, 0.f, 0.f};
    floatx4 acc5 = {0.f, 0.f, 0.f, 0.f};

    short8 ones;
#pragma unroll
    for (int i = 0; i < 8; ++i) ones[i] = (short)0x3F80;   // bf16 1.0

    const int4* adjq = (const int4*)(adj + (long)(bb * 2048 + rowbase + r15) * 2048);

    // hl staging: team-local 256 threads cover 64 f-rows x 64 j
    const int ttid = tid & 255;
    const int so = ttid >> 2, sseg = (ttid & 3) * 16;
    const unsigned short* hTsrc = hT1 + (long)(bb * 64 + so) * 2048 + sseg;
    unsigned short* hldst0 = &hl[t][0][so][sseg];
    unsigned short* hldst1 = &hl[t][1][so][sseg];

    int4 adjR[2][4];
    uint4 hrg[2][2];

#define ADJ(c) do {                                                            \
        const int base_ = (jt0 + (c)) * 16 + g * 2;                            \
        adjR[(c) & 1][0] = adjq[base_];                                        \
        adjR[(c) & 1][1] = adjq[base_ + 1];                                    \
        adjR[(c) & 1][2] = adjq[base_ + 8];                                    \
        adjR[(c) & 1][3] = adjq[base_ + 9];                                    \
    } while (0)

#define HTLOAD(c) do {                                                         \
        const unsigned short* s_ = hTsrc + (jt0 + (c)) * 64;                   \
        hrg[(c) & 1][0] = *(const uint4*)s_;                                   \
        hrg[(c) & 1][1] = *(const uint4*)(s_ + 8);                             \
    } while (0)

#define HTSTORE(c) do {                                                        \
        unsigned short* d_ = ((c) & 1) ? hldst1 : hldst0;                      \
        *(uint4*)d_ = hrg[(c) & 1][0];                                         \
        *(uint4*)(d_ + 8) = hrg[(c) & 1][1];                                   \
    } while (0)

#define COMPUTE(C) do {                                                        \
        const int vb_ = (jt0 + (C)) * 64 + g * 8;                              \
        float4 v0_ = *(const float4*)&vlds[vb_];                               \
        float4 v1_ = *(const float4*)&vlds[vb_ + 4];                           \
        float4 v2_ = *(const float4*)&vlds[vb_ + 32];                          \
        float4 v3_ = *(const float4*)&vlds[vb_ + 36];                          \
        int4 j0_ = adjR[(C) & 1][0], j1_ = adjR[(C) & 1][1];                   \
        int4 j2_ = adjR[(C) & 1][2], j3_ = adjR[(C) & 1][3];                   \
        uint4 au_, bu_;                                                        \
        au_.x = cvt_pk_bf16(j0_.x > 0 ? fmaxf(u * v0_.x, 1.f) : 0.f,           \
                            j0_.y > 0 ? fmaxf(u * v0_.y, 1.f) : 0.f);          \
        au_.y = cvt_pk_bf16(j0_.z > 0 ? fmaxf(u * v0_.z, 1.f) : 0.f,           \
                            j0_.w > 0 ? fmaxf(u * v0_.w, 1.f) : 0.f);          \
        au_.z = cvt_pk_bf16(j1_.x > 0 ? fmaxf(u * v1_.x, 1.f) : 0.f,           \
                            j1_.y > 0 ? fmaxf(u * v1_.y, 1.f) : 0.f);          \
        au_.w = cvt_pk_bf16(j1_.z > 0 ? fmaxf(u * v1_.z, 1.f) : 0.f,           \
                            j1_.w > 0 ? fmaxf(u * v1_.w, 1.f) : 0.f);          \
        bu_.x = cvt_pk_bf16(j2_.x > 0 ? fmaxf(u * v2_.x, 1.f) : 0.f,           \
                            j2_.y > 0 ? fmaxf(u * v2_.y, 1.f) : 0.f);          \
        bu_.y = cvt_pk_bf16(j2_.z > 0 ? fmaxf(u * v2_.z, 1.f) : 0.f,           \
                            j2_.w > 0 ? fmaxf(u * v2_.w, 1.f) : 0.f);          \
        bu_.z = cvt_pk_bf16(j3_.x > 0 ? fmaxf(u * v3_.x, 1.f) : 0.f,           \
                            j3_.y > 0 ? fmaxf(u * v3_.y, 1.f) : 0.f);          \
        bu_.w = cvt_pk_bf16(j3_.z > 0 ? fmaxf(u * v3_.z, 1.f) : 0.f,           \
                            j3_.w > 0 ? fmaxf(u * v3_.w, 1.f) : 0.f);          \
        short8 a0 = __builtin_bit_cast(short8, au_);                           \
        short8 a1 = __builtin_bit_cast(short8, bu_);                           \
        _Pragma("unroll")                                                      \
        for (int nt_ = 0; nt_ < 4; ++nt_) {                                    \
            short8 b0 = *(const short8*)&hl[t][(C) & 1][nt_ * 16 + r15][g * 8];      \
            short8 b1 = *(const short8*)&hl[t][(C) & 1][nt_ * 16 + r15][32 + g * 8]; \
            acc[nt_] = __builtin_amdgcn_mfma_f32_16x16x32_bf16(a0, b0, acc[nt_], 0, 0, 0); \
            acc[nt_] = __builtin_amdgcn_mfma_f32_16x16x32_bf16(a1, b1, acc[nt_], 0, 0, 0); \
        }                                                                      \
        acc5 = __builtin_amdgcn_mfma_f32_16x16x32_bf16(a0, ones, acc5, 0, 0, 0); \
        acc5 = __builtin_amdgcn_mfma_f32_16x16x32_bf16(a1, ones, acc5, 0, 0, 0); \
    } while (0)

    // prologue: adj chunks 0,1 in flight; hl[0] staged; hT chunk 1 in regs
    ADJ(0); ADJ(1);
    HTLOAD(0);
    HTSTORE(0);
    HTLOAD(1);
    team_sync();

    // NOTE: ADJ(C+2) must come AFTER COMPUTE(C) — it reuses slot adjR[C&1]
    // (WAR on the ring).
#pragma unroll
    for (int C = 0; C < 8; ++C) {
        if (C < 6) HTLOAD(C + 2);       // -> hrg[C&1] (chunk C already stored)
        if (C < 7) HTSTORE(C + 1);      // hl[(C+1)&1] <- hrg[(C+1)&1]
        COMPUTE(C);                     // reads adjR[C&1], hl[C&1]
        if (C < 6) ADJ(C + 2);          // -> adjR[C&1], after its last read
        team_sync();
    }

#undef COMPUTE
#undef HTSTORE
#undef HTLOAD
#undef ADJ

    // ---- combine 4 teams' partials (reuse hl as scratch; all computes done) ----
    float* csh = (float*)&hl[0][0][0][0];   // 12 waves x 20 x 64 f32 = 60 KB
    if (t > 0) {
        const int wb = ((t - 1) * 4 + wrow) * 20;
#pragma unroll
        for (int nt = 0; nt < 4; ++nt)
#pragma unroll
            for (int q = 0; q < 4; ++q)
                csh[(wb + nt * 4 + q) * 64 + lane] = acc[nt][q];
#pragma unroll
        for (int q = 0; q < 4; ++q)
            csh[(wb + 16 + q) * 64 + lane] = acc5[q];
    }
    __syncthreads();

    if (t == 0) {
#pragma unroll
        for (int ti = 0; ti < 3; ++ti) {
            const int wb = (ti * 4 + wrow) * 20;
#pragma unroll
            for (int nt = 0; nt < 4; ++nt)
#pragma unroll
                for (int q = 0; q < 4; ++q)
                    acc[nt][q] += csh[(wb + nt * 4 + q) * 64 + lane];
#pragma unroll
            for (int q = 0; q < 4; ++q)
                acc5[q] += csh[(wb + 16 + q) * 64 + lane];
        }
        float linv[4];
#pragma unroll
        for (int q = 0; q < 4; ++q) linv[q] = 1.0f / acc5[q];

        // h2 = x@W2^T + b2 (identity-mask layer) + store
        float xa[8], xb[8];
        const float* xrow = x + ((long)(bb * 2048 + rowbase + r15)) * 64;
#pragma unroll
        for (int e = 0; e < 8; ++e) { xa[e] = xrow[g * 8 + e]; xb[e] = xrow[32 + g * 8 + e]; }
        short8 A0 = pack8(xa), A1 = pack8(xb);
#pragma unroll
        for (int nt = 0; nt < 4; ++nt) {
            float wa[8], wb[8];
            const float* wrow2 = W2 + (nt * 16 + r15) * 64;
#pragma unroll
            for (int e = 0; e < 8; ++e) { wa[e] = wrow2[g * 8 + e]; wb[e] = wrow2[32 + g * 8 + e]; }
            short8 B0 = pack8(wa), B1 = pack8(wb);
            floatx4 c = {0.f, 0.f, 0.f, 0.f};
            c = __builtin_amdgcn_mfma_f32_16x16x32_bf16(A0, B0, c, 0, 0, 0);
            c = __builtin_amdgcn_mfma_f32_16x16x32_bf16(A1, B1, c, 0, 0, 0);
            float bias = b2[nt * 16 + r15];
#pragma unroll
            for (int q = 0; q < 4; ++q) {
                float val = acc[nt][q] * linv[q] + c[q] + bias;
                out[((long)(bb * 2048 + rowbase + 4 * g + q)) * 64 + nt * 16 + r15] = val;
            }
        }
    }
}

extern "C" void kernel_launch(void* const* d_in, const int* in_sizes, int n_in,
                              void* d_out, int out_size, void* d_ws, size_t ws_size,
                              hipStream_t stream) {
    const float* x   = (const float*)d_in[0];
    const int*   adj = (const int*)d_in[1];
    // d_in[2] identity: unused (mask == I exactly -> layer2 == h2)
    const float* W1  = (const float*)d_in[3];
    const float* b1  = (const float*)d_in[4];
    const float* a1  = (const float*)d_in[5];
    const float* ab1 = (const float*)d_in[6];
    const float* W2  = (const float*)d_in[7];
    const float* b2  = (const float*)d_in[8];
    // d_in[9] a2, d_in[10] ab2: unused

    unsigned short* hT1 = (unsigned short*)d_ws;                 // 2 MB
    float* expt1 = (float*)((char*)d_ws + (size_t)8 * 64 * 2048 * 2);
    float* expv  = expt1 + 8 * 2048;

    k_prep<<<512, 128, 0, stream>>>(x, W1, b1, a1, ab1, hT1, expt1, expv);
    k_attn<<<256, 1024, 0, stream>>>(x, adj, W2, b2, hT1, expt1, expv, (float*)d_out);
}